// Round 1
// 1192.854 us; speedup vs baseline: 1.1486x; 1.1486x over previous
//
#include <hip/hip_runtime.h>
#include <hip/hip_fp16.h>
#include <math.h>

// Problem constants
#define HD    1024      // hidden size
#define SEQL  512       // sequence length
#define NLAB  122       // labels
#define NWG   128       // workgroups in persistent recurrent kernel
#define TPW   512       // threads per WG
#define JPW   8         // h-columns (j) per workgroup  (NWG*JPW == HD)

// Workspace layout (bytes).
#define OFF_MSG   ((size_t)0)          // h msg: 2*1024 u64 (tag<<32|h_bits)    = 16384 B
#define OFF_HALL  ((size_t)16384)      // h_all: 512*1024 fp32                  = 2097152 B
#define OFF_GATES ((size_t)2113536)    // gates_x: 512*4096 fp32 (swizzled)     = 8388608 B
#define OFF_WR    ((size_t)10502144)   // W_r2: 4096*1024 fp32 (swizzled)       = 16777216 B
#define OFF_W1H   ((size_t)27279360)   // W1h: 4096*4096 fp16                   = 33554432 B
#define OFF_FH    ((size_t)60833792)   // F_h: 512*4096 fp16                    = 4194304 B
#define WS_NEED   ((size_t)65028096)

typedef unsigned long long u64;
typedef _Float16 v8h __attribute__((ext_vector_type(8)));
typedef float v4f __attribute__((ext_vector_type(4)));
typedef float v2f __attribute__((ext_vector_type(2)));
typedef unsigned int v4u __attribute__((ext_vector_type(4)));

// ---------------------------------------------------------------------------
// Prep: W_r2 laid out [g][i][t] float4 (g<128, i<16, t<512) — R4 layout for
// lstm_rec register staging. (fp32: lstm weights stay full precision.)
__global__ __launch_bounds__(256) void prep_wr(const float* __restrict__ W_ih,
                                               const float* __restrict__ W_hh,
                                               float* __restrict__ W_r2) {
    int o = blockIdx.x * 256 + threadIdx.x;   // output float4 index, < 1048576
    int g   = o >> 13;            // 16*512 float4 per g
    int i   = (o >> 9) & 15;
    int t   = o & 511;
    int row = t & 31;
    int kq  = t >> 5;
    int gate = row >> 3;
    int jj   = row & 7;
    int R = (gate << 10) + (g << 3) + jj;
    int k = (kq << 6) + (i << 2);
    float4 wa = *(const float4*)(W_ih + (size_t)R * 5120 + 4096 + k);
    float4 wb = *(const float4*)(W_hh + (size_t)R * 1024 + k);
    float4 out;
    out.x = wa.x + wb.x; out.y = wa.y + wb.y; out.z = wa.z + wb.z; out.w = wa.w + wb.w;
    *(float4*)(W_r2 + (size_t)o * 4) = out;
}

// ---------------------------------------------------------------------------
// fp16 conversions for the MFMA gates GEMM.
static __device__ __forceinline__ uint4 pack8(float4 f0, float4 f1) {
    __half2 p0 = __floats2half2_rn(f0.x, f0.y);
    __half2 p1 = __floats2half2_rn(f0.z, f0.w);
    __half2 p2 = __floats2half2_rn(f1.x, f1.y);
    __half2 p3 = __floats2half2_rn(f1.z, f1.w);
    uint4 o;
    o.x = *(unsigned*)&p0; o.y = *(unsigned*)&p1;
    o.z = *(unsigned*)&p2; o.w = *(unsigned*)&p3;
    return o;
}

// F_h[t][k] = fp16(concat(x,hi)[t][k]); one uint4 (8 halfs) per thread.
__global__ __launch_bounds__(256) void prep_fh(const float* __restrict__ x,
                                               const float* __restrict__ hi,
                                               uint4* __restrict__ F_h) {
    int o = blockIdx.x * 256 + threadIdx.x;   // < 262144
    int t = o >> 9;
    int u = o & 511;
    const float* src = (u < 256) ? (x  + (size_t)t * 2048 + u * 8)
                                 : (hi + (size_t)t * 2048 + (u - 256) * 8);
    F_h[o] = pack8(*(const float4*)src, *(const float4*)(src + 4));
}

// W1h[r][k] = fp16(W_ih[r][k]), k<4096.
__global__ __launch_bounds__(256) void prep_w1h(const float* __restrict__ W_ih,
                                                uint4* __restrict__ W1h) {
    int o = blockIdx.x * 256 + threadIdx.x;   // < 2097152
    int r = o >> 9;
    int u = o & 511;
    const float* src = W_ih + (size_t)r * 5120 + u * 8;
    W1h[o] = pack8(*(const float4*)src, *(const float4*)(src + 4));
}

// ---------------------------------------------------------------------------
// MFMA gates GEMM: G[t][r] = bias[r] + sum_k F[t][k] * W1[r][k]
// (M=512, N=4096, K=4096; both operands K-major -> gemm_bt shape.)
// 128x128 tile, BK=32, fp16 in / fp32 acc; 4 waves in 2x2 quadrants, each
// wave 4x4 subtiles of 16x16x32. Store to the R4-swizzled gates_x layout:
//   sidx(r) = ((r&1023)>>3)*32 + (r>>10)*8 + (r&7)
__global__ __launch_bounds__(256) void gates_mfma(const uint4* __restrict__ F_u4,
                                                  const uint4* __restrict__ W_u4,
                                                  const float* __restrict__ b_ih,
                                                  const float* __restrict__ b_hh,
                                                  float* __restrict__ gates_x) {
    __shared__ uint4 AsB[1024];          // As = [0,512), Bs = [512,1024)
    const _Float16* Ash = (const _Float16*)AsB;          // 4096 halfs
    const _Float16* Bsh = Ash + 4096;
    const int tid  = threadIdx.x;
    const int wv   = tid >> 6;
    const int lane = tid & 63;
    const int wr   = wv & 1;             // m quadrant
    const int wc   = wv >> 1;            // n quadrant
    const int n0 = blockIdx.x * 128;
    const int t0 = blockIdx.y * 128;

    // staging map: uint4 slot u in [0,512): row = u>>2, kpart = u&3
    const int u0 = tid * 2, u1 = tid * 2 + 1;
    const uint4* aSrc0 = F_u4 + (size_t)(t0 + (u0 >> 2)) * 512 + (u0 & 3);
    const uint4* aSrc1 = F_u4 + (size_t)(t0 + (u1 >> 2)) * 512 + (u1 & 3);
    const uint4* bSrc0 = W_u4 + (size_t)(n0 + (u0 >> 2)) * 512 + (u0 & 3);
    const uint4* bSrc1 = W_u4 + (size_t)(n0 + (u1 >> 2)) * 512 + (u1 & 3);

    v4f acc[4][4];
    #pragma unroll
    for (int mi = 0; mi < 4; ++mi)
        #pragma unroll
        for (int ni = 0; ni < 4; ++ni)
            acc[mi][ni] = (v4f){0.f, 0.f, 0.f, 0.f};

    const int aoff = (wr * 64 + (lane & 15)) * 32 + (lane >> 4) * 8;
    const int boff = (wc * 64 + (lane & 15)) * 32 + (lane >> 4) * 8;

    for (int it = 0; it < 128; ++it) {    // kb = it*32, advance 4 uint4/row
        uint4 a0 = aSrc0[it * 4], a1 = aSrc1[it * 4];
        uint4 b0 = bSrc0[it * 4], b1 = bSrc1[it * 4];
        __syncthreads();                  // prior iter's frag reads done
        AsB[u0]       = a0; AsB[u1]       = a1;
        AsB[512 + u0] = b0; AsB[512 + u1] = b1;
        __syncthreads();
        v8h a8[4], b8[4];
        #pragma unroll
        for (int mi = 0; mi < 4; ++mi)
            a8[mi] = *(const v8h*)(Ash + aoff + mi * 16 * 32);
        #pragma unroll
        for (int ni = 0; ni < 4; ++ni)
            b8[ni] = *(const v8h*)(Bsh + boff + ni * 16 * 32);
        #pragma unroll
        for (int mi = 0; mi < 4; ++mi)
            #pragma unroll
            for (int ni = 0; ni < 4; ++ni)
                acc[mi][ni] = __builtin_amdgcn_mfma_f32_16x16x32_f16(
                                  a8[mi], b8[ni], acc[mi][ni], 0, 0, 0);
    }

    // epilogue: C row (t) = t0 + wr*64 + mi*16 + (lane>>4)*4 + reg
    //           C col (r) = n0 + wc*64 + ni*16 + (lane&15)
    #pragma unroll
    for (int ni = 0; ni < 4; ++ni) {
        int r = n0 + wc * 64 + ni * 16 + (lane & 15);
        int sidx = ((r & 1023) >> 3) * 32 + (r >> 10) * 8 + (r & 7);
        float bias = b_ih[r] + b_hh[r];
        #pragma unroll
        for (int mi = 0; mi < 4; ++mi) {
            int tb = t0 + wr * 64 + mi * 16 + ((lane >> 4) << 2);
            #pragma unroll
            for (int reg = 0; reg < 4; ++reg)
                gates_x[(size_t)(tb + reg) * 4096 + sidx] = acc[mi][ni][reg] + bias;
        }
    }
}

// ---------------------------------------------------------------------------
// Fallback fp32 VALU gates GEMM (used only if ws_size < WS_NEED).
__global__ __launch_bounds__(256) void gates_gemm_f32(const float* __restrict__ x,
                                                      const float* __restrict__ hi,
                                                      const float* __restrict__ W_ih,
                                                      const float* __restrict__ b_ih,
                                                      const float* __restrict__ b_hh,
                                                      float* __restrict__ gates_x) {
    __shared__ float As[16][68];
    __shared__ float Bs[16][68];
    const int tid = threadIdx.x;
    const int r0 = blockIdx.x * 64;
    const int t0 = blockIdx.y * 64;
    const int tx = tid & 15, ty = tid >> 4;
    const int l   = tid & 63;
    const int kq4 = tid >> 6;

    float acc[4][4] = {};
    for (int kb = 0; kb < 4096; kb += 16) {
        int k = kb + kq4 * 4;
        const float* asrc = (k < 2048) ? (x  + (size_t)(t0 + l) * 2048 + k)
                                       : (hi + (size_t)(t0 + l) * 2048 + (k - 2048));
        float4 a4 = *(const float4*)asrc;
        float4 b4 = *(const float4*)(W_ih + (size_t)(r0 + l) * 5120 + k);
        __syncthreads();
        As[kq4 * 4 + 0][l] = a4.x; As[kq4 * 4 + 1][l] = a4.y;
        As[kq4 * 4 + 2][l] = a4.z; As[kq4 * 4 + 3][l] = a4.w;
        Bs[kq4 * 4 + 0][l] = b4.x; Bs[kq4 * 4 + 1][l] = b4.y;
        Bs[kq4 * 4 + 2][l] = b4.z; Bs[kq4 * 4 + 3][l] = b4.w;
        __syncthreads();
        #pragma unroll
        for (int kk = 0; kk < 16; ++kk) {
            float4 av = *(const float4*)&As[kk][ty * 4];
            float4 bv = *(const float4*)&Bs[kk][tx * 4];
            float a_[4] = {av.x, av.y, av.z, av.w};
            float b_[4] = {bv.x, bv.y, bv.z, bv.w};
            #pragma unroll
            for (int i = 0; i < 4; ++i)
                #pragma unroll
                for (int j = 0; j < 4; ++j)
                    acc[i][j] += a_[i] * b_[j];
        }
    }
    int r = r0 + tx * 4;
    float bias[4];
    #pragma unroll
    for (int j = 0; j < 4; ++j) bias[j] = b_ih[r + j] + b_hh[r + j];
    int gate = r >> 10;
    int g    = (r & 1023) >> 3;
    int jj   = r & 7;
    int sidx = g * 32 + gate * 8 + jj;
    #pragma unroll
    for (int i = 0; i < 4; ++i) {
        float4 o;
        o.x = acc[i][0] + bias[0]; o.y = acc[i][1] + bias[1];
        o.z = acc[i][2] + bias[2]; o.w = acc[i][3] + bias[3];
        *(float4*)(gates_x + (size_t)(t0 + ty * 4 + i) * 4096 + sidx) = o;
    }
}

// ---------------------------------------------------------------------------
// Persistent recurrent kernel — R5.
//   vs R4: (1) weights live in 64 VGPRs for the whole kernel (no per-step
//   128 KB LDS reload); (2) gates_x slice (64 KB) pre-staged to LDS, so the
//   per-step gx read is an LDS hit instead of a cold HBM load on the poll's
//   vmcnt(0); (3) poll is 2 coalesced global_load_dwordx4 sc1 (device-scope)
//   instead of 4×8B atomic loads; (4) the h broadcast is wave-local — each
//   wave's 64 lanes poll exactly the 128 h-values its own matvec consumes
//   (kq in {2w,2w+1} <=> floats [128w,128w+128)), same-wave DS ops are
//   in-order, so the pre-matvec __syncthreads is gone and each wave starts
//   computing on ITS slice's arrival; (5) gate activations computed one-per-
//   lane (bitwise-identical formulas) before the shuffles, so the tid<8
//   serial tail keeps only the tanh(c) chain.
//   Safety of the single barrier: wave w's partial[] write for step s+1
//   requires a remote step-s+1 publication, which transitively requires our
//   WG's step-s publication, which wave0 issues only after reading partials.
__global__ __launch_bounds__(512, 1) void lstm_rec(const float* __restrict__ gates_x,
                                                   const float* __restrict__ W_r2,
                                                   float* __restrict__ h_all,
                                                   u64* h_msg) {
    const int g   = blockIdx.x;
    const int tid = threadIdx.x;
    const int row = tid & 31;    // gate = row>>3, jj = row&7
    const int kq  = tid >> 5;    // k-slice [kq*64, kq*64+64)
    __shared__ float  gxs[SEQL * 32];   // 64 KB: this WG's gates for all steps
    __shared__ float4 h_s4[256];        // h_{s-1}; h_s4[q] = h[4q..4q+3]
    __shared__ float  partial[8][36];   // [wave][row]
    float* h_sf = (float*)h_s4;

    // Weights resident in VGPRs for the whole kernel (64 VGPRs).
    float4 w[16];
    {
        const float4* Wp = (const float4*)W_r2 + (size_t)g * 8192;
        #pragma unroll
        for (int i = 0; i < 16; ++i)
            w[i] = Wp[i * TPW + tid];
    }

    // Stage this WG's gates_x slice (512 steps x 32 rows) into LDS.
    {
        float4* gxs4 = (float4*)gxs;
        const float* gsrc = gates_x + (size_t)g * 32;
        #pragma unroll
        for (int k = 0; k < 8; ++k) {
            int o4 = tid + k * 512;           // [0, 4096)
            int s  = o4 >> 3, c4 = o4 & 7;
            gxs4[o4] = *(const float4*)(gsrc + (size_t)s * 4096 + c4 * 4);
        }
    }
    __syncthreads();

    float c = 0.f;
    int budget = 4000000;

    for (int s = 0; s < SEQL; ++s) {
        float gx = 0.f;
        if (tid < 32) gx = gxs[s * 32 + tid];

        // Poll own 2 mailbox words: one coalesced 16B device-scope load per
        // sample (wave covers a contiguous 1 KiB span -> 16 full lines).
        {
            const u64 addr = (u64)(h_msg + (size_t)(s & 1) * HD + tid * 2);
            const unsigned want = (unsigned)s;
            v4u ra, rb;
            for (;;) {
                asm volatile(
                    "global_load_dwordx4 %0, %2, off sc1\n\t"
                    "global_load_dwordx4 %1, %2, off sc1\n\t"
                    "s_waitcnt vmcnt(0)"
                    : "=&v"(ra), "=&v"(rb)
                    : "v"(addr)
                    : "memory");
                if (ra.y == want && ra.w == want) break;
                if (rb.y == want && rb.w == want) { ra = rb; break; }
                if (--budget < 0) { ra = rb; break; }
            }
            ((v2f*)h_sf)[tid] = (v2f){__uint_as_float(ra.x), __uint_as_float(ra.z)};
        }
        // Wave-local exchange: this wave's lanes wrote exactly the 128 floats
        // this wave's matvec reads; same-wave DS ops execute in order, so no
        // barrier — only a compiler reordering fence.
        asm volatile("" ::: "memory");

        float a0 = 0.f, a1 = 0.f, a2 = 0.f, a3 = 0.f;
        #pragma unroll
        for (int i = 0; i < 16; ++i) {
            float4 h4 = h_s4[kq * 16 + i];
            a0 += w[i].x * h4.x;
            a1 += w[i].y * h4.y;
            a2 += w[i].z * h4.z;
            a3 += w[i].w * h4.w;
        }
        float p = (a0 + a1) + (a2 + a3);
        p += __shfl_xor(p, 32, 64);
        if ((tid & 32) == 0)
            partial[tid >> 6][row] = p;
        __syncthreads();

        if (tid < 32) {
            float sum = gx;
            #pragma unroll
            for (int q = 0; q < 8; ++q) sum += partial[q][tid];
            // Per-lane activation, bitwise-identical formulas to R4:
            // rows 0-7 i, 8-15 f (sigmoid), 16-23 g (tanh), 24-31 o (sigmoid)
            bool isg = ((tid >> 3) == 2);
            float e   = __expf(isg ? -2.f * sum : -sum);
            float act = isg ? (2.f / (1.f + e) - 1.f) : (1.f / (1.f + e));
            int jj = tid & 7;
            float sf = __shfl(act,  8 + jj, 64);
            float tg = __shfl(act, 16 + jj, 64);
            float so = __shfl(act, 24 + jj, 64);
            if (tid < 8) {
                float si = act;
                c = sf * c + si * tg;
                float th = 2.f / (1.f + __expf(-2.f * c)) - 1.f;
                float h = so * th;
                int j = g * JPW + tid;
                h_all[(size_t)s * HD + j] = h;
                u64 m = ((u64)(unsigned)(s + 1) << 32)
                      | (u64)__float_as_uint(h);
                __hip_atomic_store(h_msg + (size_t)((s + 1) & 1) * HD + j, m,
                                   __ATOMIC_RELAXED, __HIP_MEMORY_SCOPE_AGENT);
            }
        }
    }
}

// ---------------------------------------------------------------------------
// out[t][lab] = b_fc[lab] + sum_k h_all[t][k] * W_fc[lab][k]
__global__ __launch_bounds__(128) void fc_out(const float* __restrict__ h_all,
                                              const float* __restrict__ W_fc,
                                              const float* __restrict__ b_fc,
                                              float* __restrict__ out) {
    const int t = blockIdx.x;
    const int tid = threadIdx.x;
    __shared__ float4 h_s[256];
    const float4* hsrc = (const float4*)(h_all + (size_t)t * HD);
    h_s[tid] = hsrc[tid];
    h_s[tid + 128] = hsrc[tid + 128];
    __syncthreads();
    if (tid < NLAB) {
        float acc = b_fc[tid];
        const float4* wp = (const float4*)(W_fc + (size_t)tid * HD);
        #pragma unroll 8
        for (int k4 = 0; k4 < 256; ++k4) {
            float4 w = wp[k4];
            float4 h = h_s[k4];
            acc += w.x*h.x + w.y*h.y + w.z*h.z + w.w*h.w;
        }
        out[(size_t)t * NLAB + tid] = acc;
    }
}

// ---------------------------------------------------------------------------
extern "C" void kernel_launch(void* const* d_in, const int* in_sizes, int n_in,
                              void* d_out, int out_size, void* d_ws, size_t ws_size,
                              hipStream_t stream) {
    const float* x    = (const float*)d_in[0];
    const float* hi   = (const float*)d_in[1];
    const float* W_ih = (const float*)d_in[2];
    const float* W_hh = (const float*)d_in[3];
    const float* b_ih = (const float*)d_in[4];
    const float* b_hh = (const float*)d_in[5];
    const float* W_fc = (const float*)d_in[6];
    const float* b_fc = (const float*)d_in[7];
    float* out = (float*)d_out;

    char* ws = (char*)d_ws;
    u64*   h_msg   = (u64*)(ws + OFF_MSG);
    float* h_all   = (float*)(ws + OFF_HALL);
    float* gates_x = (float*)(ws + OFF_GATES);
    float* W_r2    = (float*)(ws + OFF_WR);
    uint4* W1h     = (uint4*)(ws + OFF_W1H);
    uint4* F_h     = (uint4*)(ws + OFF_FH);

    // zero the mailbox: h_{-1}=0 with tag 0 (ws re-poisoned 0xAA each call)
    hipMemsetAsync(d_ws, 0, 16384, stream);

    prep_wr<<<4096, 256, 0, stream>>>(W_ih, W_hh, W_r2);

    if (ws_size >= WS_NEED) {
        prep_fh<<<1024, 256, 0, stream>>>(x, hi, F_h);
        prep_w1h<<<8192, 256, 0, stream>>>(W_ih, W1h);
        dim3 gg(32, 4);   // n-tiles x t-tiles
        gates_mfma<<<gg, 256, 0, stream>>>(F_h, W1h, b_ih, b_hh, gates_x);
    } else {
        dim3 gg(64, 8);
        gates_gemm_f32<<<gg, 256, 0, stream>>>(x, hi, W_ih, b_ih, b_hh, gates_x);
    }

    lstm_rec<<<NWG, TPW, 0, stream>>>(gates_x, W_r2, h_all, h_msg);

    fc_out<<<SEQL, 128, 0, stream>>>(h_all, W_fc, b_fc, out);
}

// Round 2
// 1155.888 us; speedup vs baseline: 1.1854x; 1.0320x over previous
//
#include <hip/hip_runtime.h>
#include <hip/hip_fp16.h>
#include <math.h>

// Problem constants
#define HD    1024      // hidden size
#define SEQL  512       // sequence length
#define NLAB  122       // labels
#define NWG   128       // workgroups in persistent recurrent kernel
#define TPW   512       // threads per WG
#define JPW   8         // h-columns (j) per workgroup  (NWG*JPW == HD)

// Workspace layout (bytes).
#define OFF_MSG   ((size_t)0)          // h msg: 2*1024 u64 (tag<<32|h_bits)    = 16384 B
#define OFF_HALL  ((size_t)16384)      // h_all: 512*1024 fp32                  = 2097152 B
#define OFF_GATES ((size_t)2113536)    // gates_x: 512*4096 fp32 (swizzled)     = 8388608 B
#define OFF_WR    ((size_t)10502144)   // W_r2: 4096*1024 fp32 (swizzled)       = 16777216 B
#define OFF_W1H   ((size_t)27279360)   // W1h: 4096*4096 fp16                   = 33554432 B
#define OFF_FH    ((size_t)60833792)   // F_h: 512*4096 fp16                    = 4194304 B
#define WS_NEED   ((size_t)65028096)

typedef unsigned long long u64;
typedef _Float16 v8h __attribute__((ext_vector_type(8)));
typedef float v4f __attribute__((ext_vector_type(4)));
typedef float v2f __attribute__((ext_vector_type(2)));
typedef unsigned int v4u __attribute__((ext_vector_type(4)));

// ---------------------------------------------------------------------------
// Prep: W_r2 laid out [g][i][t] float4 (g<128, i<16, t<512) — R4 layout for
// lstm_rec LDS staging. (fp32: lstm weights stay full precision.)
__global__ __launch_bounds__(256) void prep_wr(const float* __restrict__ W_ih,
                                               const float* __restrict__ W_hh,
                                               float* __restrict__ W_r2) {
    int o = blockIdx.x * 256 + threadIdx.x;   // output float4 index, < 1048576
    int g   = o >> 13;            // 16*512 float4 per g
    int i   = (o >> 9) & 15;
    int t   = o & 511;
    int row = t & 31;
    int kq  = t >> 5;
    int gate = row >> 3;
    int jj   = row & 7;
    int R = (gate << 10) + (g << 3) + jj;
    int k = (kq << 6) + (i << 2);
    float4 wa = *(const float4*)(W_ih + (size_t)R * 5120 + 4096 + k);
    float4 wb = *(const float4*)(W_hh + (size_t)R * 1024 + k);
    float4 out;
    out.x = wa.x + wb.x; out.y = wa.y + wb.y; out.z = wa.z + wb.z; out.w = wa.w + wb.w;
    *(float4*)(W_r2 + (size_t)o * 4) = out;
}

// ---------------------------------------------------------------------------
// fp16 conversions for the MFMA gates GEMM.
static __device__ __forceinline__ uint4 pack8(float4 f0, float4 f1) {
    __half2 p0 = __floats2half2_rn(f0.x, f0.y);
    __half2 p1 = __floats2half2_rn(f0.z, f0.w);
    __half2 p2 = __floats2half2_rn(f1.x, f1.y);
    __half2 p3 = __floats2half2_rn(f1.z, f1.w);
    uint4 o;
    o.x = *(unsigned*)&p0; o.y = *(unsigned*)&p1;
    o.z = *(unsigned*)&p2; o.w = *(unsigned*)&p3;
    return o;
}

// F_h[t][k] = fp16(concat(x,hi)[t][k]); one uint4 (8 halfs) per thread.
__global__ __launch_bounds__(256) void prep_fh(const float* __restrict__ x,
                                               const float* __restrict__ hi,
                                               uint4* __restrict__ F_h) {
    int o = blockIdx.x * 256 + threadIdx.x;   // < 262144
    int t = o >> 9;
    int u = o & 511;
    const float* src = (u < 256) ? (x  + (size_t)t * 2048 + u * 8)
                                 : (hi + (size_t)t * 2048 + (u - 256) * 8);
    F_h[o] = pack8(*(const float4*)src, *(const float4*)(src + 4));
}

// W1h[r][k] = fp16(W_ih[r][k]), k<4096.
__global__ __launch_bounds__(256) void prep_w1h(const float* __restrict__ W_ih,
                                                uint4* __restrict__ W1h) {
    int o = blockIdx.x * 256 + threadIdx.x;   // < 2097152
    int r = o >> 9;
    int u = o & 511;
    const float* src = W_ih + (size_t)r * 5120 + u * 8;
    W1h[o] = pack8(*(const float4*)src, *(const float4*)(src + 4));
}

// ---------------------------------------------------------------------------
// MFMA gates GEMM: G[t][r] = bias[r] + sum_k F[t][k] * W1[r][k]
// (M=512, N=4096, K=4096; both operands K-major -> gemm_bt shape.)
// 128x128 tile, BK=32, fp16 in / fp32 acc; 4 waves in 2x2 quadrants, each
// wave 4x4 subtiles of 16x16x32. Store to the R4-swizzled gates_x layout:
//   sidx(r) = ((r&1023)>>3)*32 + (r>>10)*8 + (r&7)
__global__ __launch_bounds__(256) void gates_mfma(const uint4* __restrict__ F_u4,
                                                  const uint4* __restrict__ W_u4,
                                                  const float* __restrict__ b_ih,
                                                  const float* __restrict__ b_hh,
                                                  float* __restrict__ gates_x) {
    __shared__ uint4 AsB[1024];          // As = [0,512), Bs = [512,1024)
    const _Float16* Ash = (const _Float16*)AsB;          // 4096 halfs
    const _Float16* Bsh = Ash + 4096;
    const int tid  = threadIdx.x;
    const int wv   = tid >> 6;
    const int lane = tid & 63;
    const int wr   = wv & 1;             // m quadrant
    const int wc   = wv >> 1;            // n quadrant
    const int n0 = blockIdx.x * 128;
    const int t0 = blockIdx.y * 128;

    // staging map: uint4 slot u in [0,512): row = u>>2, kpart = u&3
    const int u0 = tid * 2, u1 = tid * 2 + 1;
    const uint4* aSrc0 = F_u4 + (size_t)(t0 + (u0 >> 2)) * 512 + (u0 & 3);
    const uint4* aSrc1 = F_u4 + (size_t)(t0 + (u1 >> 2)) * 512 + (u1 & 3);
    const uint4* bSrc0 = W_u4 + (size_t)(n0 + (u0 >> 2)) * 512 + (u0 & 3);
    const uint4* bSrc1 = W_u4 + (size_t)(n0 + (u1 >> 2)) * 512 + (u1 & 3);

    v4f acc[4][4];
    #pragma unroll
    for (int mi = 0; mi < 4; ++mi)
        #pragma unroll
        for (int ni = 0; ni < 4; ++ni)
            acc[mi][ni] = (v4f){0.f, 0.f, 0.f, 0.f};

    const int aoff = (wr * 64 + (lane & 15)) * 32 + (lane >> 4) * 8;
    const int boff = (wc * 64 + (lane & 15)) * 32 + (lane >> 4) * 8;

    for (int it = 0; it < 128; ++it) {    // kb = it*32, advance 4 uint4/row
        uint4 a0 = aSrc0[it * 4], a1 = aSrc1[it * 4];
        uint4 b0 = bSrc0[it * 4], b1 = bSrc1[it * 4];
        __syncthreads();                  // prior iter's frag reads done
        AsB[u0]       = a0; AsB[u1]       = a1;
        AsB[512 + u0] = b0; AsB[512 + u1] = b1;
        __syncthreads();
        v8h a8[4], b8[4];
        #pragma unroll
        for (int mi = 0; mi < 4; ++mi)
            a8[mi] = *(const v8h*)(Ash + aoff + mi * 16 * 32);
        #pragma unroll
        for (int ni = 0; ni < 4; ++ni)
            b8[ni] = *(const v8h*)(Bsh + boff + ni * 16 * 32);
        #pragma unroll
        for (int mi = 0; mi < 4; ++mi)
            #pragma unroll
            for (int ni = 0; ni < 4; ++ni)
                acc[mi][ni] = __builtin_amdgcn_mfma_f32_16x16x32_f16(
                                  a8[mi], b8[ni], acc[mi][ni], 0, 0, 0);
    }

    // epilogue: C row (t) = t0 + wr*64 + mi*16 + (lane>>4)*4 + reg
    //           C col (r) = n0 + wc*64 + ni*16 + (lane&15)
    #pragma unroll
    for (int ni = 0; ni < 4; ++ni) {
        int r = n0 + wc * 64 + ni * 16 + (lane & 15);
        int sidx = ((r & 1023) >> 3) * 32 + (r >> 10) * 8 + (r & 7);
        float bias = b_ih[r] + b_hh[r];
        #pragma unroll
        for (int mi = 0; mi < 4; ++mi) {
            int tb = t0 + wr * 64 + mi * 16 + ((lane >> 4) << 2);
            #pragma unroll
            for (int reg = 0; reg < 4; ++reg)
                gates_x[(size_t)(tb + reg) * 4096 + sidx] = acc[mi][ni][reg] + bias;
        }
    }
}

// ---------------------------------------------------------------------------
// Fallback fp32 VALU gates GEMM (used only if ws_size < WS_NEED).
__global__ __launch_bounds__(256) void gates_gemm_f32(const float* __restrict__ x,
                                                      const float* __restrict__ hi,
                                                      const float* __restrict__ W_ih,
                                                      const float* __restrict__ b_ih,
                                                      const float* __restrict__ b_hh,
                                                      float* __restrict__ gates_x) {
    __shared__ float As[16][68];
    __shared__ float Bs[16][68];
    const int tid = threadIdx.x;
    const int r0 = blockIdx.x * 64;
    const int t0 = blockIdx.y * 64;
    const int tx = tid & 15, ty = tid >> 4;
    const int l   = tid & 63;
    const int kq4 = tid >> 6;

    float acc[4][4] = {};
    for (int kb = 0; kb < 4096; kb += 16) {
        int k = kb + kq4 * 4;
        const float* asrc = (k < 2048) ? (x  + (size_t)(t0 + l) * 2048 + k)
                                       : (hi + (size_t)(t0 + l) * 2048 + (k - 2048));
        float4 a4 = *(const float4*)asrc;
        float4 b4 = *(const float4*)(W_ih + (size_t)(r0 + l) * 5120 + k);
        __syncthreads();
        As[kq4 * 4 + 0][l] = a4.x; As[kq4 * 4 + 1][l] = a4.y;
        As[kq4 * 4 + 2][l] = a4.z; As[kq4 * 4 + 3][l] = a4.w;
        Bs[kq4 * 4 + 0][l] = b4.x; Bs[kq4 * 4 + 1][l] = b4.y;
        Bs[kq4 * 4 + 2][l] = b4.z; Bs[kq4 * 4 + 3][l] = b4.w;
        __syncthreads();
        #pragma unroll
        for (int kk = 0; kk < 16; ++kk) {
            float4 av = *(const float4*)&As[kk][ty * 4];
            float4 bv = *(const float4*)&Bs[kk][tx * 4];
            float a_[4] = {av.x, av.y, av.z, av.w};
            float b_[4] = {bv.x, bv.y, bv.z, bv.w};
            #pragma unroll
            for (int i = 0; i < 4; ++i)
                #pragma unroll
                for (int j = 0; j < 4; ++j)
                    acc[i][j] += a_[i] * b_[j];
        }
    }
    int r = r0 + tx * 4;
    float bias[4];
    #pragma unroll
    for (int j = 0; j < 4; ++j) bias[j] = b_ih[r + j] + b_hh[r + j];
    int gate = r >> 10;
    int g    = (r & 1023) >> 3;
    int jj   = r & 7;
    int sidx = g * 32 + gate * 8 + jj;
    #pragma unroll
    for (int i = 0; i < 4; ++i) {
        float4 o;
        o.x = acc[i][0] + bias[0]; o.y = acc[i][1] + bias[1];
        o.z = acc[i][2] + bias[2]; o.w = acc[i][3] + bias[3];
        *(float4*)(gates_x + (size_t)(t0 + ty * 4 + i) * 4096 + sidx) = o;
    }
}

// ---------------------------------------------------------------------------
// Persistent recurrent kernel — R6.
//   vs R5: (1) weights BACK in LDS (R4 layout) — R5's VGPR_Count=56 showed
//   the compiler rematerialized the "register-resident" weights as per-step
//   global reloads on the post-arrival critical path; LDS weights are read
//   PRE-POLL each step (h-independent), so their latency hides under the
//   mailbox wait. (2) gx prefetched into a register pre-poll (plain global
//   load, L3-hit, latency hidden) — frees LDS so the 128 KB weights fit.
//   (3) poll traffic cut ~4x: single dwordx4 sample per iteration (the
//   lane's two u64 are contiguous) + s_sleep(2) backoff after the first
//   miss — R5's 8 waves x 2 KB continuous polling ~= 8 TB/s of L3 traffic,
//   congesting the fabric and inflating its own roundtrip.
//   Kept from R5: wave-local h exchange (no pre-matvec barrier), per-lane
//   activations, single barrier per step (safety argument unchanged).
__global__ __launch_bounds__(512, 1) void lstm_rec(const float* __restrict__ gates_x,
                                                   const float* __restrict__ W_r2,
                                                   float* __restrict__ h_all,
                                                   u64* h_msg) {
    const int g   = blockIdx.x;
    const int tid = threadIdx.x;
    const int row = tid & 31;    // gate = row>>3, jj = row&7
    const int kq  = tid >> 5;    // k-slice [kq*64, kq*64+64)
    __shared__ float4 W_lds[16][TPW];   // 128 KB, lane-contiguous
    __shared__ float4 h_s4[256];        // h_{s-1}; h_s4[q] = h[4q..4q+3]
    __shared__ float  partial[8][36];   // [wave][row]
    float* h_sf = (float*)h_s4;

    {
        const float4* Wp = (const float4*)W_r2 + (size_t)g * 8192;
        #pragma unroll
        for (int i = 0; i < 16; ++i)
            W_lds[i][tid] = Wp[i * TPW + tid];
    }
    __syncthreads();

    float c = 0.f;
    int budget = 4000000;

    for (int s = 0; s < SEQL; ++s) {
        // --- pre-poll: issue all h-independent loads; latency hides under
        // the mailbox wait -----------------------------------------------
        float gx = 0.f;
        if (tid < 32)
            gx = gates_x[(size_t)s * 4096 + g * 32 + tid];

        asm volatile("" ::: "memory");
        float4 w[16];
        #pragma unroll
        for (int i = 0; i < 16; ++i)
            w[i] = W_lds[i][tid];
        asm volatile("" ::: "memory");

        // --- poll own 2 mailbox words: ONE coalesced 16B device-scope load
        // per sample; immediate retry once, then s_sleep(2) (~128 cy) to
        // keep aggregate fabric traffic low -------------------------------
        {
            const u64 addr = (u64)(h_msg + (size_t)(s & 1) * HD + tid * 2);
            const unsigned want = (unsigned)s;
            v4u ra;
            int miss = 0;
            for (;;) {
                asm volatile(
                    "global_load_dwordx4 %0, %1, off sc1\n\t"
                    "s_waitcnt vmcnt(0)"
                    : "=&v"(ra)
                    : "v"(addr)
                    : "memory");
                if (ra.y == want && ra.w == want) break;
                if (--budget < 0) break;
                if (miss++) __builtin_amdgcn_s_sleep(2);
            }
            ((v2f*)h_sf)[tid] = (v2f){__uint_as_float(ra.x), __uint_as_float(ra.z)};
        }
        // Wave-local exchange: this wave's lanes wrote exactly the 128 floats
        // this wave's matvec reads; same-wave DS ops execute in order, so no
        // barrier — only a compiler reordering fence.
        asm volatile("" ::: "memory");

        float a0 = 0.f, a1 = 0.f, a2 = 0.f, a3 = 0.f;
        #pragma unroll
        for (int i = 0; i < 16; ++i) {
            float4 h4 = h_s4[kq * 16 + i];
            a0 += w[i].x * h4.x;
            a1 += w[i].y * h4.y;
            a2 += w[i].z * h4.z;
            a3 += w[i].w * h4.w;
        }
        float p = (a0 + a1) + (a2 + a3);
        p += __shfl_xor(p, 32, 64);
        if ((tid & 32) == 0)
            partial[tid >> 6][row] = p;
        __syncthreads();

        if (tid < 32) {
            float sum = gx;
            #pragma unroll
            for (int q = 0; q < 8; ++q) sum += partial[q][tid];
            // Per-lane activation, bitwise-identical formulas:
            // rows 0-7 i, 8-15 f (sigmoid), 16-23 g (tanh), 24-31 o (sigmoid)
            bool isg = ((tid >> 3) == 2);
            float e   = __expf(isg ? -2.f * sum : -sum);
            float act = isg ? (2.f / (1.f + e) - 1.f) : (1.f / (1.f + e));
            int jj = tid & 7;
            float sf = __shfl(act,  8 + jj, 64);
            float tg = __shfl(act, 16 + jj, 64);
            float so = __shfl(act, 24 + jj, 64);
            if (tid < 8) {
                float si = act;
                c = sf * c + si * tg;
                float th = 2.f / (1.f + __expf(-2.f * c)) - 1.f;
                float h = so * th;
                int j = g * JPW + tid;
                h_all[(size_t)s * HD + j] = h;
                u64 m = ((u64)(unsigned)(s + 1) << 32)
                      | (u64)__float_as_uint(h);
                __hip_atomic_store(h_msg + (size_t)((s + 1) & 1) * HD + j, m,
                                   __ATOMIC_RELAXED, __HIP_MEMORY_SCOPE_AGENT);
            }
        }
    }
}

// ---------------------------------------------------------------------------
// out[t][lab] = b_fc[lab] + sum_k h_all[t][k] * W_fc[lab][k]
__global__ __launch_bounds__(128) void fc_out(const float* __restrict__ h_all,
                                              const float* __restrict__ W_fc,
                                              const float* __restrict__ b_fc,
                                              float* __restrict__ out) {
    const int t = blockIdx.x;
    const int tid = threadIdx.x;
    __shared__ float4 h_s[256];
    const float4* hsrc = (const float4*)(h_all + (size_t)t * HD);
    h_s[tid] = hsrc[tid];
    h_s[tid + 128] = hsrc[tid + 128];
    __syncthreads();
    if (tid < NLAB) {
        float acc = b_fc[tid];
        const float4* wp = (const float4*)(W_fc + (size_t)tid * HD);
        #pragma unroll 8
        for (int k4 = 0; k4 < 256; ++k4) {
            float4 w = wp[k4];
            float4 h = h_s[k4];
            acc += w.x*h.x + w.y*h.y + w.z*h.z + w.w*h.w;
        }
        out[(size_t)t * NLAB + tid] = acc;
    }
}

// ---------------------------------------------------------------------------
extern "C" void kernel_launch(void* const* d_in, const int* in_sizes, int n_in,
                              void* d_out, int out_size, void* d_ws, size_t ws_size,
                              hipStream_t stream) {
    const float* x    = (const float*)d_in[0];
    const float* hi   = (const float*)d_in[1];
    const float* W_ih = (const float*)d_in[2];
    const float* W_hh = (const float*)d_in[3];
    const float* b_ih = (const float*)d_in[4];
    const float* b_hh = (const float*)d_in[5];
    const float* W_fc = (const float*)d_in[6];
    const float* b_fc = (const float*)d_in[7];
    float* out = (float*)d_out;

    char* ws = (char*)d_ws;
    u64*   h_msg   = (u64*)(ws + OFF_MSG);
    float* h_all   = (float*)(ws + OFF_HALL);
    float* gates_x = (float*)(ws + OFF_GATES);
    float* W_r2    = (float*)(ws + OFF_WR);
    uint4* W1h     = (uint4*)(ws + OFF_W1H);
    uint4* F_h     = (uint4*)(ws + OFF_FH);

    // zero the mailbox: h_{-1}=0 with tag 0 (ws re-poisoned 0xAA each call)
    hipMemsetAsync(d_ws, 0, 16384, stream);

    prep_wr<<<4096, 256, 0, stream>>>(W_ih, W_hh, W_r2);

    if (ws_size >= WS_NEED) {
        prep_fh<<<1024, 256, 0, stream>>>(x, hi, F_h);
        prep_w1h<<<8192, 256, 0, stream>>>(W_ih, W1h);
        dim3 gg(32, 4);   // n-tiles x t-tiles
        gates_mfma<<<gg, 256, 0, stream>>>(F_h, W1h, b_ih, b_hh, gates_x);
    } else {
        dim3 gg(64, 8);
        gates_gemm_f32<<<gg, 256, 0, stream>>>(x, hi, W_ih, b_ih, b_hh, gates_x);
    }

    lstm_rec<<<NWG, TPW, 0, stream>>>(gates_x, W_r2, h_all, h_msg);

    fc_out<<<SEQL, 128, 0, stream>>>(h_all, W_fc, b_fc, out);
}